// Round 9
// baseline (1696.265 us; speedup 1.0000x reference)
//
#include <hip/hip_runtime.h>
#include <math.h>

// QMixtralAttention — fp32 in/out (runtime-detected, bf16 fallback).
// Numerics: integer-exact quantized GEMMs (bf16-int MFMA, per-partition scale
// fold), split-bf16 (hi+lo) flash attention, fp32 attention output.
// R1: XOR-swizzled K/V LDS tiles in attn_k (16-way bank conflict -> 2-way).
// R2: KVBLK=32 2-phase — REGRESSED (softmax amortization). Reverted.
// R3: 8-wave/128-row block — NEUTRAL (FETCH -15%, chain unchanged).
// R4: V-from-global + XCD decode — REGRESSED 2x (FETCH 10x). Reverted.
// R5: K/V double-buffer @KVBLK=64 (128 KiB LDS) — WIN (590->562 µs attn).
// R6: causal-pairing (uniform 36 tiles/block) — WIN (1915->1695 total).
// R7: XOR-swizzle on gemm_core LDS — conflicts 5.03e7 -> 0, gemm -7.5%.
// R8: double-buffered gemm_core (LDS 32->64 KiB; VGPR already caps at
//     2 blocks/CU so no occupancy cost). Flattened 64-iter K-loop:
//     GSTAGE(it+1, buf^1) -> compute(buf) -> scale-fold at partition
//     boundary (it==51/59/63) -> ONE __syncthreads -> swap. The vmcnt(0)
//     drain now waits on loads issued a full compute phase earlier.

typedef unsigned short u16;
typedef __bf16 bf16x8 __attribute__((ext_vector_type(8)));
typedef float f32x4 __attribute__((ext_vector_type(4)));

#define S_ 2048
#define NEG_BIG (-1e30f)

__device__ __forceinline__ float bf2f(u16 u) {
  union { unsigned int i; float f; } w; w.i = ((unsigned int)u) << 16; return w.f;
}
__device__ __forceinline__ u16 f2bf(float f) {
  union { float f; unsigned int i; } w; w.f = f;
  unsigned int i = w.i;
  i += ((i >> 16) & 1u) + 0x7fffu;  // RNE
  return (u16)(i >> 16);
}
// flag: 0 = bf16 input, 1 = fp32 input
__device__ __forceinline__ float loadf(const void* X, size_t j, int flag) {
  return flag ? ((const float*)X)[j] : bf2f(((const u16*)X)[j]);
}

#define GLDS16(g, l) __builtin_amdgcn_global_load_lds( \
    (__attribute__((address_space(1))) void*)(g),      \
    (__attribute__((address_space(3))) void*)(l), 16, 0, 0)

__global__ void detect_k(const u16* __restrict__ cosRaw, int* __restrict__ flag) {
  if (threadIdx.x == 0) *flag = (cosRaw[0] == 0x3F80u) ? 0 : 1;
}

// ---------------------------------------------------------------------------
// Quantize + permute: Y[row][j] = clip(rint(X[row][idx[j]]/s_p)) as bf16 INT,
// scales written to Sout[row*3+p]. Partitions: [0,3328) q7, [3328,3840) q31,
// [3840,4096) q127.
// ---------------------------------------------------------------------------
__device__ __forceinline__ float block_max(float x, float* sred, int t) {
#pragma unroll
  for (int o = 32; o > 0; o >>= 1) x = fmaxf(x, __shfl_xor(x, o));
  __syncthreads();
  if ((t & 63) == 0) sred[t >> 6] = x;
  __syncthreads();
  return fmaxf(fmaxf(sred[0], sred[1]), fmaxf(sred[2], sred[3]));
}

__global__ __launch_bounds__(256) void quant_permute_k(
    const void* __restrict__ X, const int* __restrict__ idx, u16* __restrict__ Y,
    float* __restrict__ Sout, const int* __restrict__ flagp, int mode /*1=force fp32*/)
{
  int flag = mode ? 1 : *flagp;
  int row = blockIdx.x;
  int t = threadIdx.x;
  size_t base = (size_t)row * 4096;
  u16* yr = Y + base;
  float v[16];
#pragma unroll
  for (int i = 0; i < 16; i++) v[i] = loadf(X, base + idx[i * 256 + t], flag);
  float m0 = 0.f;
#pragma unroll
  for (int i = 0; i < 13; i++) m0 = fmaxf(m0, fabsf(v[i]));
  float m1 = fmaxf(fabsf(v[13]), fabsf(v[14]));
  float m2 = fabsf(v[15]);
  __shared__ float sred[4];
  float M0 = block_max(m0, sred, t);
  float M1 = block_max(m1, sred, t);
  float M2 = block_max(m2, sred, t);
  float s0 = M0 / 7.f + 1e-8f;
  float s1 = M1 / 31.f + 1e-8f;
  float s2 = M2 / 127.f + 1e-8f;
#pragma unroll
  for (int i = 0; i < 16; i++) {
    float s, qm;
    if (i < 13)      { s = s0; qm = 7.f; }
    else if (i < 15) { s = s1; qm = 31.f; }
    else             { s = s2; qm = 127.f; }
    float q = rintf(v[i] / s);
    q = fminf(fmaxf(q, -qm), qm);
    yr[i * 256 + t] = f2bf(q);   // small integer: exact in bf16
  }
  if (t == 0) { Sout[row * 3] = s0; Sout[row * 3 + 1] = s1; Sout[row * 3 + 2] = s2; }
}

// ---------------------------------------------------------------------------
// Integer GEMM core: C[M][N] += sum_p Sa[m,p]*Sb[n,p]*(Aint_p · Bint_p^T)
// 128x128 tile, BK=64, 64 K-iters; partitions end at iters 51/59/63 where
// the per-partition scale fold runs (register-only).
// R7: LDS XOR-swizzle (source col pre-swizzled, reads XOR (l15&7)<<3).
// R8: double-buffered (As/Bs are [2][128*64]); one barrier per K-iter;
//     STAGE(it+1) issued before compute(it) so the barrier's vmcnt(0) drain
//     is covered by the compute phase.
// ---------------------------------------------------------------------------
__device__ __forceinline__ int colbase_of(int wave, int ni, int ropemap) {
  return ropemap ? (((wave >> 1) << 5) + ((ni & 1) << 4) + ((ni >> 1) << 6))
                 : (((wave >> 1) << 6) + (ni << 4));
}

__device__ __forceinline__ void gemm_core(
    const u16* __restrict__ A, const u16* __restrict__ Bm,
    const float* __restrict__ Sa, const float* __restrict__ Sb,
    int bm, int bn, int tid, int ropemap,
    u16* As, u16* Bs, f32x4 C[4][4])
{
  int wave = tid >> 6, lane = tid & 63;
  int l15 = lane & 15, quad = lane >> 4;
  int wm = (wave & 1) << 6;
  // Staging dest (linear, per GLDS16): row = wave*32 + i*8 + (lane>>3),
  // col(u16) = (lane&7)*8. row&7 = lane>>3 -> source col slot pre-swizzled.
  int gsw = ((lane & 7) ^ (lane >> 3)) << 3;
  const u16* Ag = A + (size_t)(bm * 128 + wave * 32 + (lane >> 3)) * 4096 + gsw;
  const u16* Bg = Bm + (size_t)(bn * 128 + wave * 32 + (lane >> 3)) * 4096 + gsw;
  int woff = wave * 32 * 64;
  int swz = (l15 & 7) << 3;   // read-side XOR (u16 units)
  f32x4 acc[4][4] = {};
  int cb[4];
#pragma unroll
  for (int ni = 0; ni < 4; ni++) cb[ni] = colbase_of(wave, ni, ropemap);

#define GSTAGE(IT, BUF) do {                                          \
    int _k0 = (IT) * 64;                                              \
    u16* _a = As + (BUF) * 8192 + woff;                               \
    u16* _b = Bs + (BUF) * 8192 + woff;                               \
    _Pragma("unroll")                                                 \
    for (int i = 0; i < 4; i++) {                                     \
      GLDS16(Ag + _k0 + (size_t)(i * 8) * 4096, _a + i * 8 * 64);     \
      GLDS16(Bg + _k0 + (size_t)(i * 8) * 4096, _b + i * 8 * 64);     \
    }                                                                 \
  } while (0)

  GSTAGE(0, 0);
  __syncthreads();
  int cur = 0, p = 0;
#pragma unroll 1
  for (int it = 0; it < 64; ++it) {
    if (it + 1 < 64) GSTAGE(it + 1, cur ^ 1);  // prefetch next K-tile
    const u16* Ac = As + cur * 8192;
    const u16* Bc = Bs + cur * 8192;
#pragma unroll
    for (int kk = 0; kk < 2; kk++) {
      bf16x8 af[4], bfv[4];
#pragma unroll
      for (int mi = 0; mi < 4; mi++)
        af[mi] = *(const bf16x8*)(Ac + (wm + mi * 16 + l15) * 64 + ((kk * 32 + quad * 8) ^ swz));
#pragma unroll
      for (int ni = 0; ni < 4; ni++)
        bfv[ni] = *(const bf16x8*)(Bc + (cb[ni] + l15) * 64 + ((kk * 32 + quad * 8) ^ swz));
#pragma unroll
      for (int mi = 0; mi < 4; mi++)
#pragma unroll
        for (int ni = 0; ni < 4; ni++)
          acc[mi][ni] = __builtin_amdgcn_mfma_f32_16x16x32_bf16(af[mi], bfv[ni], acc[mi][ni], 0, 0, 0);
    }
    if (it == 51 || it == 59 || it == 63) {
      // partition boundary: fold scales into C (register-only)
      float sb[4];
#pragma unroll
      for (int ni = 0; ni < 4; ni++) sb[ni] = Sb[(size_t)(bn * 128 + cb[ni] + l15) * 3 + p];
#pragma unroll
      for (int mi = 0; mi < 4; mi++)
#pragma unroll
        for (int r = 0; r < 4; r++) {
          float sa = Sa[(size_t)(bm * 128 + wm + mi * 16 + quad * 4 + r) * 3 + p];
#pragma unroll
          for (int ni = 0; ni < 4; ni++) {
            C[mi][ni][r] += sa * sb[ni] * acc[mi][ni][r];
            acc[mi][ni][r] = 0.f;
          }
        }
      p++;
    }
    // one barrier per K-iter: drains GSTAGE(it+1) (issued a compute phase
    // ago) AND fences buf[cur] reads before iter it+1 stages into it.
    __syncthreads();
    cur ^= 1;
  }
#undef GSTAGE
}

// GEMM + fused RoPE + scale + hi/lo split epilogue (Q and K projections).
__global__ __launch_bounds__(256) void gemm_rope_k(
    const u16* __restrict__ A, const u16* __restrict__ Bm,
    const float* __restrict__ Sa, const float* __restrict__ Sb,
    const void* __restrict__ Co, const void* __restrict__ Si,
    const int* __restrict__ flagp, u16* __restrict__ Qh, u16* __restrict__ Ql,
    int N, float scale)
{
  __shared__ __align__(16) u16 As[2 * 128 * 64];
  __shared__ __align__(16) u16 Bs[2 * 128 * 64];
  f32x4 C[4][4] = {};
  int tid = threadIdx.x;
  gemm_core(A, Bm, Sa, Sb, blockIdx.x, blockIdx.y, tid, 1, As, Bs, C);
  int wave = tid >> 6, lane = tid & 63, l15 = lane & 15, quad = lane >> 4;
  int wm = (wave & 1) << 6;
  int flag = *flagp;
#pragma unroll
  for (int mi = 0; mi < 4; mi++)
#pragma unroll
    for (int ni = 0; ni < 2; ni++) {
      int d1 = colbase_of(wave, ni, 1) + l15;  // < 64
#pragma unroll
      for (int r = 0; r < 4; r++) {
        int row = blockIdx.x * 128 + wm + mi * 16 + quad * 4 + r;
        float x1 = C[mi][ni][r], x2 = C[mi][ni + 2][r];
        size_t ci = (size_t)row * 128 + d1;
        float c1 = loadf(Co, ci, flag),      s1 = loadf(Si, ci, flag);
        float c2 = loadf(Co, ci + 64, flag), s2 = loadf(Si, ci + 64, flag);
        float y1 = (x1 * c1 - x2 * s1) * scale;
        float y2 = (x2 * c2 + x1 * s2) * scale;
        size_t o1 = (size_t)row * N + blockIdx.y * 128 + d1;
        u16 h1 = f2bf(y1); Qh[o1] = h1; Ql[o1] = f2bf(y1 - bf2f(h1));
        u16 h2 = f2bf(y2); Qh[o1 + 64] = h2; Ql[o1 + 64] = f2bf(y2 - bf2f(h2));
      }
    }
}

// GEMM + fused transpose + hi/lo split epilogue (V projection).
__global__ __launch_bounds__(256) void gemm_vt_k(
    const u16* __restrict__ A, const u16* __restrict__ Bm,
    const float* __restrict__ Sa, const float* __restrict__ Sb,
    u16* __restrict__ Vh, u16* __restrict__ Vl)
{
  __shared__ __align__(16) u16 As[2 * 128 * 64];
  __shared__ __align__(16) u16 Bs[2 * 128 * 64];
  f32x4 C[4][4] = {};
  int tid = threadIdx.x;
  gemm_core(A, Bm, Sa, Sb, blockIdx.x, blockIdx.y, tid, 0, As, Bs, C);
  int wave = tid >> 6, lane = tid & 63, l15 = lane & 15, quad = lane >> 4;
  int wm = (wave & 1) << 6;
#pragma unroll
  for (int mi = 0; mi < 4; mi++)
#pragma unroll
    for (int ni = 0; ni < 4; ni++) {
      int c = blockIdx.y * 128 + colbase_of(wave, ni, 0) + l15;
#pragma unroll
      for (int r = 0; r < 4; r++) {
        int row = blockIdx.x * 128 + wm + mi * 16 + quad * 4 + r;
        int b = row >> 11, s = row & 2047;
        float v = C[mi][ni][r];
        size_t o = ((size_t)(b * 1024 + c)) * 2048 + s;
        u16 h = f2bf(v); Vh[o] = h; Vl[o] = f2bf(v - bf2f(h));
      }
    }
}

// GEMM + output write (fp32 or bf16 per detected flag).
__global__ __launch_bounds__(256) void gemm_out_k(
    const u16* __restrict__ A, const u16* __restrict__ Bm,
    const float* __restrict__ Sa, const float* __restrict__ Sb,
    const int* __restrict__ flagp, void* __restrict__ Cout)
{
  __shared__ __align__(16) u16 As[2 * 128 * 64];
  __shared__ __align__(16) u16 Bs[2 * 128 * 64];
  f32x4 C[4][4] = {};
  int tid = threadIdx.x;
  gemm_core(A, Bm, Sa, Sb, blockIdx.x, blockIdx.y, tid, 0, As, Bs, C);
  int wave = tid >> 6, lane = tid & 63, l15 = lane & 15, quad = lane >> 4;
  int wm = (wave & 1) << 6;
  int flag = *flagp;
#pragma unroll
  for (int mi = 0; mi < 4; mi++)
#pragma unroll
    for (int ni = 0; ni < 4; ni++) {
      int col = blockIdx.y * 128 + colbase_of(wave, ni, 0) + l15;
#pragma unroll
      for (int r = 0; r < 4; r++) {
        int row = blockIdx.x * 128 + wm + mi * 16 + quad * 4 + r;
        if (flag) ((float*)Cout)[(size_t)row * 4096 + col] = C[mi][ni][r];
        else      ((u16*)Cout)[(size_t)row * 4096 + col] = f2bf(C[mi][ni][r]);
      }
    }
}

// ---------------------------------------------------------------------------
// Causal flash attention, split-bf16 (3-term MFMA) QK^T and PV. O is fp32.
// R6 structure: R5 (8 waves, 128 q-rows/segment, KVBLK=64, double-buffered
// K/V, 128 KiB LDS) + causal PAIRING: each block runs two segments,
// q-tile qb (blockIdx.x in 0..7) then q-tile 15-qb. Staged tiles/block =
// (2qb+2)+(2(15-qb)+2) = 36 for every block -> perfectly uniform grid of
// 512 blocks (2 rounds/CU at 1 block/CU). Per tile t (within a segment):
//   STAGE(t+1 -> buf^1); QK + softmax(defer-max); __syncthreads;
//   P write (aliases K[cur]) + PV; __syncthreads.
// Swizzles (rule #21, pre-swizzled global source): K [64][128] and
// V [128][64] and P [16][64]: slot(16B) ^= row&7; read XOR = (l15&7)<<3.
// ---------------------------------------------------------------------------
__global__ __launch_bounds__(512) void attn_k(
    const u16* __restrict__ Qh, const u16* __restrict__ Ql,
    const u16* __restrict__ Kh, const u16* __restrict__ Kl,
    const u16* __restrict__ Vh, const u16* __restrict__ Vl,
    float* __restrict__ O)
{
  __shared__ __align__(16) u16 Ksh[2][64 * 128];
  __shared__ __align__(16) u16 Ksl[2][64 * 128];
  __shared__ __align__(16) u16 Vsh[2][128 * 64];
  __shared__ __align__(16) u16 Vsl[2][128 * 64];
  int tid = threadIdx.x, wave = tid >> 6, lane = tid & 63;
  int l15 = lane & 15, quad = lane >> 4;
  int qp = blockIdx.x, h = blockIdx.y, b = blockIdx.z;  // qp in 0..7
  int kvh = h >> 2;

  // K staging: instr i in {0,1}: dest row = wave*4 + i*32 + (lane>>4),
  // dest col(u16) = l15*8. Source pre-swizzled by ((row&7)<<3).
  int krow = wave * 4 + (lane >> 4);
  size_t koff = (size_t)(b * S_ + krow) * 1024 + kvh * 128
              + ((l15 * 8) ^ ((krow & 7) << 3));
  // V staging: dest row = wave*8 + i*64 + (lane>>3), dest slot = lane&7.
  int vrow = lane >> 3;  // 0..7
  size_t voff = ((size_t)(b * 1024 + kvh * 128 + wave * 8 + vrow)) * 2048
              + (size_t)(((lane & 7) ^ vrow) << 3);
  const u16* Kgh = Kh + koff;
  const u16* Kgl = Kl + koff;
  const u16* Vgh = Vh + voff;
  const u16* Vgl = Vl + voff;

  int swz = (l15 & 7) << 3;        // read-side XOR (u16 units), all tiles

#define STAGE(T, BUF) do {                                                   \
    size_t _k0 = (size_t)(T) * 64;                                           \
    GLDS16(Kgh + _k0 * 1024,              &Ksh[BUF][(wave * 4) * 128]);      \
    GLDS16(Kgh + (_k0 + 32) * 1024,       &Ksh[BUF][(wave * 4 + 32) * 128]); \
    GLDS16(Kgl + _k0 * 1024,              &Ksl[BUF][(wave * 4) * 128]);      \
    GLDS16(Kgl + (_k0 + 32) * 1024,       &Ksl[BUF][(wave * 4 + 32) * 128]); \
    GLDS16(Vgh + _k0,                     &Vsh[BUF][(wave * 8) * 64]);       \
    GLDS16(Vgh + (size_t)64 * 2048 + _k0, &Vsh[BUF][(wave * 8 + 64) * 64]);  \
    GLDS16(Vgl + _k0,                     &Vsl[BUF][(wave * 8) * 64]);       \
    GLDS16(Vgl + (size_t)64 * 2048 + _k0, &Vsl[BUF][(wave * 8 + 64) * 64]);  \
  } while (0)

#pragma unroll 1
  for (int seg = 0; seg < 2; ++seg) {
    int qb = seg ? (15 - qp) : qp;
    int q0 = qb * 128 + wave * 16;

    bf16x8 qfh[4], qfl[4];
    const u16* qrow = Qh + (size_t)(b * S_ + q0 + l15) * 4096 + h * 128 + quad * 8;
    const u16* qrol = Ql + (size_t)(b * S_ + q0 + l15) * 4096 + h * 128 + quad * 8;
#pragma unroll
    for (int c = 0; c < 4; c++) {
      qfh[c] = *(const bf16x8*)(qrow + c * 32);
      qfl[c] = *(const bf16x8*)(qrol + c * 32);
    }
    float m_i[4], l_i[4];
#pragma unroll
    for (int r = 0; r < 4; r++) { m_i[r] = NEG_BIG; l_i[r] = 0.f; }
    f32x4 oacc[8] = {};

    int nt = 2 * qb + 2;   // number of 64-key tiles this segment
    STAGE(0, 0);
    __syncthreads();
    int cur = 0;
#pragma unroll 1
    for (int t = 0; t < nt; ++t) {
      if (t + 1 < nt) STAGE(t + 1, cur ^ 1);  // prefetch next tile first
      const u16* Kch = Ksh[cur];
      const u16* Kcl = Ksl[cur];
      const u16* Vch = Vsh[cur];
      const u16* Vcl = Vsl[cur];
      u16* PhW = Ksh[cur] + wave * 1024;  // P aliases K[cur] after mid barrier
      u16* PlW = Ksl[cur] + wave * 1024;
      int k0 = t * 64;
      bool active = (k0 <= q0 + 15);      // wave-uniform causal skip
      float p[4][4];
      if (active) {
        // ---- QK^T ----
        f32x4 sacc[4] = {};
        __builtin_amdgcn_s_setprio(1);
#pragma unroll
        for (int c = 0; c < 4; c++) {
#pragma unroll
          for (int ntl = 0; ntl < 4; ntl++) {
            int off = (ntl * 16 + l15) * 128 + ((c * 32 + quad * 8) ^ swz);
            bf16x8 kh = *(const bf16x8*)(Kch + off);
            bf16x8 kl = *(const bf16x8*)(Kcl + off);
            sacc[ntl] = __builtin_amdgcn_mfma_f32_16x16x32_bf16(qfh[c], kh, sacc[ntl], 0, 0, 0);
            sacc[ntl] = __builtin_amdgcn_mfma_f32_16x16x32_bf16(qfh[c], kl, sacc[ntl], 0, 0, 0);
            sacc[ntl] = __builtin_amdgcn_mfma_f32_16x16x32_bf16(qfl[c], kh, sacc[ntl], 0, 0, 0);
          }
        }
        __builtin_amdgcn_s_setprio(0);
        // ---- online softmax with defer-max (T13, THR=8) ----
        float cmax = NEG_BIG;
#pragma unroll
        for (int r = 0; r < 4; r++) {
          int qg = q0 + quad * 4 + r;
#pragma unroll
          for (int ntl = 0; ntl < 4; ntl++) {
            int kg = k0 + ntl * 16 + l15;
            float sv = (kg <= qg) ? sacc[ntl][r] : NEG_BIG;
            sacc[ntl][r] = sv;
            cmax = fmaxf(cmax, sv - m_i[r]);
          }
        }
        if (__all(cmax <= 8.0f)) {
          // deferred: keep m_i, no rescale (P bounded by e^8)
#pragma unroll
          for (int r = 0; r < 4; r++) {
            float ps = 0.f;
#pragma unroll
            for (int ntl = 0; ntl < 4; ntl++) {
              float pv = __expf(sacc[ntl][r] - m_i[r]);
              p[ntl][r] = pv;
              ps += pv;
            }
#pragma unroll
            for (int o = 8; o > 0; o >>= 1) ps += __shfl_xor(ps, o);
            l_i[r] += ps;
          }
        } else {
          float alpha[4];
#pragma unroll
          for (int r = 0; r < 4; r++) {
            float mr = m_i[r];
#pragma unroll
            for (int ntl = 0; ntl < 4; ntl++) mr = fmaxf(mr, sacc[ntl][r]);
#pragma unroll
            for (int o = 8; o > 0; o >>= 1) mr = fmaxf(mr, __shfl_xor(mr, o));
            float a = __expf(m_i[r] - mr);
            alpha[r] = a;
            float ps = 0.f;
#pragma unroll
            for (int ntl = 0; ntl < 4; ntl++) {
              float pv = __expf(sacc[ntl][r] - mr);
              p[ntl][r] = pv;
              ps += pv;
            }
#pragma unroll
            for (int o = 8; o > 0; o >>= 1) ps += __shfl_xor(ps, o);
            l_i[r] = l_i[r] * a + ps;
            m_i[r] = mr;
          }
#pragma unroll
          for (int dt = 0; dt < 8; dt++)
#pragma unroll
            for (int r = 0; r < 4; r++) oacc[dt][r] *= alpha[r];
        }
      }
      // mid barrier: all QK reads of K[cur] done -> safe to alias with P.
      // vmcnt(0) drain here waits on STAGE(t+1) issued a full phase ago.
      __syncthreads();
      if (active) {
        // ---- P write (per-wave region, XOR-swizzled stride-64) ----
#pragma unroll
        for (int ntl = 0; ntl < 4; ntl++)
#pragma unroll
          for (int r = 0; r < 4; r++) {
            float pv = p[ntl][r];
            u16 ph = f2bf(pv);
            int row = quad * 4 + r;
            int o = row * 64 + ((ntl * 16 + l15) ^ ((row & 7) << 3));
            PhW[o] = ph;
            PlW[o] = f2bf(pv - bf2f(ph));
          }
        // ---- PV ----
#pragma unroll
        for (int kt = 0; kt < 2; kt++) {
          bf16x8 pfh = *(const bf16x8*)(PhW + l15 * 64 + ((kt * 32 + quad * 8) ^ swz));
          bf16x8 pfl = *(const bf16x8*)(PlW + l15 * 64 + ((kt * 32 + quad * 8) ^ swz));
          __builtin_amdgcn_s_setprio(1);
#pragma unroll
          for (int dt = 0; dt < 8; dt++) {
            int off = (dt * 16 + l15) * 64 + ((kt * 32 + quad * 8) ^ swz);
            bf16x8 vh = *(const bf16x8*)(Vch + off);
            bf16x8 vl = *(const bf16x8*)(Vcl + off);
            oacc[dt] = __builtin_amdgcn_mfma_f32_16x16x32_bf16(pfh, vh, oacc[dt], 0, 0, 0);
            oacc[dt] = __builtin_amdgcn_mfma_f32_16x16x32_bf16(pfh, vl, oacc[dt], 0, 0, 0);
            oacc[dt] = __builtin_amdgcn_mfma_f32_16x16x32_bf16(pfl, vh, oacc[dt], 0, 0, 0);
          }
          __builtin_amdgcn_s_setprio(0);
        }
      }
      // end barrier: PV reads of V[cur] and P(=K[cur] alias) complete before
      // the next iteration's STAGE(t+2) overwrites this buffer.
      __syncthreads();
      cur ^= 1;
    }
    // ---- segment epilogue: write O for this q-tile ----
#pragma unroll
    for (int dt = 0; dt < 8; dt++)
#pragma unroll
      for (int r = 0; r < 4; r++) {
        int qg = q0 + quad * 4 + r;
        float ov = oacc[dt][r] / fmaxf(l_i[r], 1e-30f);
        O[(size_t)(b * S_ + qg) * 4096 + h * 128 + dt * 16 + l15] = ov;
      }
  }
#undef STAGE
}

// ---------------------------------------------------------------------------
extern "C" void kernel_launch(void* const* d_in, const int* in_sizes, int n_in,
                              void* d_out, int out_size, void* d_ws, size_t ws_size,
                              hipStream_t stream)
{
  const void* hidden = d_in[0];
  const void* cosT   = d_in[1];
  const void* sinT   = d_in[2];
  const void* Wq     = d_in[3];
  const void* Wk     = d_in[4];
  const void* Wv     = d_in[5];
  const void* Wo     = d_in[6];
  const int* idx_q  = (const int*)d_in[7];
  const int* idx_k  = (const int*)d_in[8];
  const int* idx_v  = (const int*)d_in[9];
  const int* idx_o  = (const int*)d_in[10];

  char* ws = (char*)d_ws;
  const size_t MB = 1048576;
  int*   flag = (int*)ws;
  float* Sa   = (float*)(ws + MB);            // 48 KiB
  float* Sb   = (float*)(ws + MB + 512 * 1024);
  u16* Xi  = (u16*)(ws + 2 * MB);    // 32 MiB (A-int)
  u16* Wi  = (u16*)(ws + 34 * MB);   // 32 MiB (B-int)
  u16* Khi = (u16*)(ws + 66 * MB);   // 8
  u16* Klo = (u16*)(ws + 74 * MB);   // 8
  u16* Vhi = (u16*)(ws + 82 * MB);   // 8
  u16* Vlo = (u16*)(ws + 90 * MB);   // 8
  u16* Qhi = (u16*)(ws + 98 * MB);   // 32
  u16* Qlo = (u16*)(ws + 130 * MB);  // 32  (total 162 MiB)
  float* AO = (float*)(ws + 2 * MB); // 64, overlays Xi+Wi (dead by then)
  u16* Oq  = Qhi;   // overlays Q (dead after attention)
  u16* Woq = Qlo;

  detect_k<<<1, 64, 0, stream>>>((const u16*)cosT, flag);

  // K projection (+RoPE, split)
  quant_permute_k<<<4096, 256, 0, stream>>>(hidden, idx_k, Xi, Sa, flag, 0);
  quant_permute_k<<<1024, 256, 0, stream>>>(Wk, idx_k, Wi, Sb, flag, 0);
  gemm_rope_k<<<dim3(32, 8), 256, 0, stream>>>(Xi, Wi, Sa, Sb, cosT, sinT, flag, Khi, Klo, 1024, 1.0f);
  // V projection (+transpose, split)
  quant_permute_k<<<4096, 256, 0, stream>>>(hidden, idx_v, Xi, Sa, flag, 0);
  quant_permute_k<<<1024, 256, 0, stream>>>(Wv, idx_v, Wi, Sb, flag, 0);
  gemm_vt_k<<<dim3(32, 8), 256, 0, stream>>>(Xi, Wi, Sa, Sb, Vhi, Vlo);
  // Q projection (+RoPE+scale, split)
  quant_permute_k<<<4096, 256, 0, stream>>>(hidden, idx_q, Xi, Sa, flag, 0);
  quant_permute_k<<<4096, 256, 0, stream>>>(Wq, idx_q, Wi, Sb, flag, 0);
  gemm_rope_k<<<dim3(32, 32), 256, 0, stream>>>(Xi, Wi, Sa, Sb, cosT, sinT, flag, Qhi, Qlo, 4096, 0.08838834764831843f);
  // attention (paired causal tiles: qp pairs (qp, 15-qp) -> uniform blocks)
  attn_k<<<dim3(8, 32, 2), 512, 0, stream>>>(Qhi, Qlo, Khi, Klo, Vhi, Vlo, AO);
  // output projection
  quant_permute_k<<<4096, 256, 0, stream>>>(AO, idx_o, Oq, Sa, flag, 1);
  quant_permute_k<<<4096, 256, 0, stream>>>(Wo, idx_o, Woq, Sb, flag, 0);
  gemm_out_k<<<dim3(32, 32), 256, 0, stream>>>(Oq, Woq, Sa, Sb, flag, d_out);
}

// Round 10
// 1265.443 us; speedup vs baseline: 1.3405x; 1.3405x over previous
//
#include <hip/hip_runtime.h>
#include <math.h>

// QMixtralAttention — fp32 in/out (runtime-detected, bf16 fallback).
// Numerics: integer-exact quantized GEMMs (int8 MFMA, i32 accum, per-partition
// scale fold), split-bf16 (hi+lo) flash attention, fp32 attention output.
// R1: XOR-swizzled K/V LDS tiles in attn_k (16-way bank conflict -> 2-way).
// R2: KVBLK=32 2-phase — REGRESSED (softmax amortization). Reverted.
// R3: 8-wave/128-row block — NEUTRAL. R4: V-from-global — REGRESSED 2x.
// R5: attn K/V double-buffer — WIN (590->562). R6: causal-pairing — WIN
//     (1915->1695). R7: gemm LDS swizzle — conflicts 5e7->0, gemm -7.5%.
// R8: gemm double-buffer — REGRESSED (m99/m100 null reproduced: implicit
//     wave overlap at 2 blocks/CU already covers staging; dbuf added VALU
//     overhead). Reverted to R7 structure.
// R9: GEMM datapath bf16 -> INT8 (mfma_i32_16x16x64_i8, i32 accum exact).
//     Quantized values fit i8 by construction (|q|<=127). Staged bytes/FLOP
//     halve -> BK=128, K-iters 64->32 on a stage-bound loop; MFMA count
//     halves at ~2x rate. Partitions 3328/512/256 = 26/4/2 iters of 128.
//     Scale fold: C += sa*sb*(float)acc_i32 per partition. Attn unchanged.

typedef unsigned short u16;
typedef signed char i8;
typedef __bf16 bf16x8 __attribute__((ext_vector_type(8)));
typedef float f32x4 __attribute__((ext_vector_type(4)));
typedef int i32x4 __attribute__((ext_vector_type(4)));

#define S_ 2048
#define NEG_BIG (-1e30f)

__device__ __forceinline__ float bf2f(u16 u) {
  union { unsigned int i; float f; } w; w.i = ((unsigned int)u) << 16; return w.f;
}
__device__ __forceinline__ u16 f2bf(float f) {
  union { float f; unsigned int i; } w; w.f = f;
  unsigned int i = w.i;
  i += ((i >> 16) & 1u) + 0x7fffu;  // RNE
  return (u16)(i >> 16);
}
// flag: 0 = bf16 input, 1 = fp32 input
__device__ __forceinline__ float loadf(const void* X, size_t j, int flag) {
  return flag ? ((const float*)X)[j] : bf2f(((const u16*)X)[j]);
}

#define GLDS16(g, l) __builtin_amdgcn_global_load_lds( \
    (__attribute__((address_space(1))) void*)(g),      \
    (__attribute__((address_space(3))) void*)(l), 16, 0, 0)

__global__ void detect_k(const u16* __restrict__ cosRaw, int* __restrict__ flag) {
  if (threadIdx.x == 0) *flag = (cosRaw[0] == 0x3F80u) ? 0 : 1;
}

// ---------------------------------------------------------------------------
// Quantize + permute: Y[row][j] = clip(rint(X[row][idx[j]]/s_p)) as INT8,
// scales written to Sout[row*3+p]. Partitions: [0,3328) q7, [3328,3840) q31,
// [3840,4096) q127.
// ---------------------------------------------------------------------------
__device__ __forceinline__ float block_max(float x, float* sred, int t) {
#pragma unroll
  for (int o = 32; o > 0; o >>= 1) x = fmaxf(x, __shfl_xor(x, o));
  __syncthreads();
  if ((t & 63) == 0) sred[t >> 6] = x;
  __syncthreads();
  return fmaxf(fmaxf(sred[0], sred[1]), fmaxf(sred[2], sred[3]));
}

__global__ __launch_bounds__(256) void quant_permute_k(
    const void* __restrict__ X, const int* __restrict__ idx, i8* __restrict__ Y,
    float* __restrict__ Sout, const int* __restrict__ flagp, int mode /*1=force fp32*/)
{
  int flag = mode ? 1 : *flagp;
  int row = blockIdx.x;
  int t = threadIdx.x;
  size_t base = (size_t)row * 4096;
  i8* yr = Y + base;
  float v[16];
#pragma unroll
  for (int i = 0; i < 16; i++) v[i] = loadf(X, base + idx[i * 256 + t], flag);
  float m0 = 0.f;
#pragma unroll
  for (int i = 0; i < 13; i++) m0 = fmaxf(m0, fabsf(v[i]));
  float m1 = fmaxf(fabsf(v[13]), fabsf(v[14]));
  float m2 = fabsf(v[15]);
  __shared__ float sred[4];
  float M0 = block_max(m0, sred, t);
  float M1 = block_max(m1, sred, t);
  float M2 = block_max(m2, sred, t);
  float s0 = M0 / 7.f + 1e-8f;
  float s1 = M1 / 31.f + 1e-8f;
  float s2 = M2 / 127.f + 1e-8f;
#pragma unroll
  for (int i = 0; i < 16; i++) {
    float s, qm;
    if (i < 13)      { s = s0; qm = 7.f; }
    else if (i < 15) { s = s1; qm = 31.f; }
    else             { s = s2; qm = 127.f; }
    float q = rintf(v[i] / s);
    q = fminf(fmaxf(q, -qm), qm);
    yr[i * 256 + t] = (i8)(int)q;   // small integer: exact in int8
  }
  if (t == 0) { Sout[row * 3] = s0; Sout[row * 3 + 1] = s1; Sout[row * 3 + 2] = s2; }
}

// ---------------------------------------------------------------------------
// Integer GEMM core (INT8): C[M][N] += sum_p Sa[m,p]*Sb[n,p]*(A_p · B_p^T)
// 128x128 tile, BK=128 (i8), phases of 26/4/2 BK-iters (partition boundaries
// 3328/512/256). mfma_i32_16x16x64_i8, i32 accumulation (exact).
// LDS tiles [128 rows][128 B], XOR-swizzled in 16B slots (rule #21):
// staging source col slot ^= dest row&7 (= lane>>3); reads XOR (l15&7)<<4.
// R8 dbuf reverted: single-buffer, 2 barriers/iter (implicit wave overlap
// at 2 blocks/CU covers staging latency — R8 measured).
// ---------------------------------------------------------------------------
__device__ __forceinline__ int colbase_of(int wave, int ni, int ropemap) {
  return ropemap ? (((wave >> 1) << 5) + ((ni & 1) << 4) + ((ni >> 1) << 6))
                 : (((wave >> 1) << 6) + (ni << 4));
}

__device__ __forceinline__ void gemm_core(
    const i8* __restrict__ A, const i8* __restrict__ Bm,
    const float* __restrict__ Sa, const float* __restrict__ Sb,
    int bm, int bn, int tid, int ropemap,
    i8* As, i8* Bs, f32x4 C[4][4])
{
  int wave = tid >> 6, lane = tid & 63;
  int l15 = lane & 15, quad = lane >> 4;
  int wm = (wave & 1) << 6;
  // Staging dest (linear, per GLDS16): row = wave*32 + i*8 + (lane>>3),
  // col slot = lane&7 (16B slots). row&7 = lane>>3 -> source slot pre-XORed.
  int gsw = ((lane & 7) ^ (lane >> 3)) << 4;   // bytes
  const i8* Ag = A + (size_t)(bm * 128 + wave * 32 + (lane >> 3)) * 4096 + gsw;
  const i8* Bg = Bm + (size_t)(bn * 128 + wave * 32 + (lane >> 3)) * 4096 + gsw;
  i8* AsW = As + wave * 32 * 128;
  i8* BsW = Bs + wave * 32 * 128;
  int swz = (l15 & 7) << 4;   // read-side XOR (bytes)
  i32x4 acc[4][4] = {};
  int cb[4];
#pragma unroll
  for (int ni = 0; ni < 4; ni++) cb[ni] = colbase_of(wave, ni, ropemap);
  int k0 = 0;
#pragma unroll 1
  for (int p = 0; p < 3; p++) {
    int iters = (p == 0) ? 26 : (p == 1 ? 4 : 2);
#pragma unroll 1
    for (int it = 0; it < iters; it++, k0 += 128) {
#pragma unroll
      for (int i = 0; i < 4; i++) {
        GLDS16(Ag + k0 + (size_t)(i * 8) * 4096, AsW + i * 8 * 128);
        GLDS16(Bg + k0 + (size_t)(i * 8) * 4096, BsW + i * 8 * 128);
      }
      __syncthreads();
#pragma unroll
      for (int kk = 0; kk < 2; kk++) {
        i32x4 af[4], bfv[4];
#pragma unroll
        for (int mi = 0; mi < 4; mi++)
          af[mi] = *(const i32x4*)(As + (wm + mi * 16 + l15) * 128 + ((kk * 64 + quad * 16) ^ swz));
#pragma unroll
        for (int ni = 0; ni < 4; ni++)
          bfv[ni] = *(const i32x4*)(Bs + (cb[ni] + l15) * 128 + ((kk * 64 + quad * 16) ^ swz));
#pragma unroll
        for (int mi = 0; mi < 4; mi++)
#pragma unroll
          for (int ni = 0; ni < 4; ni++)
            acc[mi][ni] = __builtin_amdgcn_mfma_i32_16x16x64_i8(af[mi], bfv[ni], acc[mi][ni], 0, 0, 0);
      }
      __syncthreads();
    }
    // partition boundary: fold scales into C (i32 -> f32, exact sums)
    float sb[4];
#pragma unroll
    for (int ni = 0; ni < 4; ni++) sb[ni] = Sb[(size_t)(bn * 128 + cb[ni] + l15) * 3 + p];
#pragma unroll
    for (int mi = 0; mi < 4; mi++)
#pragma unroll
      for (int r = 0; r < 4; r++) {
        float sa = Sa[(size_t)(bm * 128 + wm + mi * 16 + quad * 4 + r) * 3 + p];
#pragma unroll
        for (int ni = 0; ni < 4; ni++) {
          C[mi][ni][r] += sa * sb[ni] * (float)acc[mi][ni][r];
          acc[mi][ni][r] = 0;
        }
      }
  }
}

// GEMM + fused RoPE + scale + hi/lo split epilogue (Q and K projections).
__global__ __launch_bounds__(256) void gemm_rope_k(
    const i8* __restrict__ A, const i8* __restrict__ Bm,
    const float* __restrict__ Sa, const float* __restrict__ Sb,
    const void* __restrict__ Co, const void* __restrict__ Si,
    const int* __restrict__ flagp, u16* __restrict__ Qh, u16* __restrict__ Ql,
    int N, float scale)
{
  __shared__ __align__(16) i8 As[128 * 128];
  __shared__ __align__(16) i8 Bs[128 * 128];
  f32x4 C[4][4] = {};
  int tid = threadIdx.x;
  gemm_core(A, Bm, Sa, Sb, blockIdx.x, blockIdx.y, tid, 1, As, Bs, C);
  int wave = tid >> 6, lane = tid & 63, l15 = lane & 15, quad = lane >> 4;
  int wm = (wave & 1) << 6;
  int flag = *flagp;
#pragma unroll
  for (int mi = 0; mi < 4; mi++)
#pragma unroll
    for (int ni = 0; ni < 2; ni++) {
      int d1 = colbase_of(wave, ni, 1) + l15;  // < 64
#pragma unroll
      for (int r = 0; r < 4; r++) {
        int row = blockIdx.x * 128 + wm + mi * 16 + quad * 4 + r;
        float x1 = C[mi][ni][r], x2 = C[mi][ni + 2][r];
        size_t ci = (size_t)row * 128 + d1;
        float c1 = loadf(Co, ci, flag),      s1 = loadf(Si, ci, flag);
        float c2 = loadf(Co, ci + 64, flag), s2 = loadf(Si, ci + 64, flag);
        float y1 = (x1 * c1 - x2 * s1) * scale;
        float y2 = (x2 * c2 + x1 * s2) * scale;
        size_t o1 = (size_t)row * N + blockIdx.y * 128 + d1;
        u16 h1 = f2bf(y1); Qh[o1] = h1; Ql[o1] = f2bf(y1 - bf2f(h1));
        u16 h2 = f2bf(y2); Qh[o1 + 64] = h2; Ql[o1 + 64] = f2bf(y2 - bf2f(h2));
      }
    }
}

// GEMM + fused transpose + hi/lo split epilogue (V projection).
__global__ __launch_bounds__(256) void gemm_vt_k(
    const i8* __restrict__ A, const i8* __restrict__ Bm,
    const float* __restrict__ Sa, const float* __restrict__ Sb,
    u16* __restrict__ Vh, u16* __restrict__ Vl)
{
  __shared__ __align__(16) i8 As[128 * 128];
  __shared__ __align__(16) i8 Bs[128 * 128];
  f32x4 C[4][4] = {};
  int tid = threadIdx.x;
  gemm_core(A, Bm, Sa, Sb, blockIdx.x, blockIdx.y, tid, 0, As, Bs, C);
  int wave = tid >> 6, lane = tid & 63, l15 = lane & 15, quad = lane >> 4;
  int wm = (wave & 1) << 6;
#pragma unroll
  for (int mi = 0; mi < 4; mi++)
#pragma unroll
    for (int ni = 0; ni < 4; ni++) {
      int c = blockIdx.y * 128 + colbase_of(wave, ni, 0) + l15;
#pragma unroll
      for (int r = 0; r < 4; r++) {
        int row = blockIdx.x * 128 + wm + mi * 16 + quad * 4 + r;
        int b = row >> 11, s = row & 2047;
        float v = C[mi][ni][r];
        size_t o = ((size_t)(b * 1024 + c)) * 2048 + s;
        u16 h = f2bf(v); Vh[o] = h; Vl[o] = f2bf(v - bf2f(h));
      }
    }
}

// GEMM + output write (fp32 or bf16 per detected flag).
__global__ __launch_bounds__(256) void gemm_out_k(
    const i8* __restrict__ A, const i8* __restrict__ Bm,
    const float* __restrict__ Sa, const float* __restrict__ Sb,
    const int* __restrict__ flagp, void* __restrict__ Cout)
{
  __shared__ __align__(16) i8 As[128 * 128];
  __shared__ __align__(16) i8 Bs[128 * 128];
  f32x4 C[4][4] = {};
  int tid = threadIdx.x;
  gemm_core(A, Bm, Sa, Sb, blockIdx.x, blockIdx.y, tid, 0, As, Bs, C);
  int wave = tid >> 6, lane = tid & 63, l15 = lane & 15, quad = lane >> 4;
  int wm = (wave & 1) << 6;
  int flag = *flagp;
#pragma unroll
  for (int mi = 0; mi < 4; mi++)
#pragma unroll
    for (int ni = 0; ni < 4; ni++) {
      int col = blockIdx.y * 128 + colbase_of(wave, ni, 0) + l15;
#pragma unroll
      for (int r = 0; r < 4; r++) {
        int row = blockIdx.x * 128 + wm + mi * 16 + quad * 4 + r;
        if (flag) ((float*)Cout)[(size_t)row * 4096 + col] = C[mi][ni][r];
        else      ((u16*)Cout)[(size_t)row * 4096 + col] = f2bf(C[mi][ni][r]);
      }
    }
}

// ---------------------------------------------------------------------------
// Causal flash attention, split-bf16 (3-term MFMA) QK^T and PV. O is fp32.
// R6 structure (unchanged): 8 waves, 128 q-rows/segment, KVBLK=64, double-
// buffered K/V (128 KiB LDS), causal pairing (qb, 15-qb) -> uniform 36
// staged tiles/block, 512-block grid.
// ---------------------------------------------------------------------------
__global__ __launch_bounds__(512) void attn_k(
    const u16* __restrict__ Qh, const u16* __restrict__ Ql,
    const u16* __restrict__ Kh, const u16* __restrict__ Kl,
    const u16* __restrict__ Vh, const u16* __restrict__ Vl,
    float* __restrict__ O)
{
  __shared__ __align__(16) u16 Ksh[2][64 * 128];
  __shared__ __align__(16) u16 Ksl[2][64 * 128];
  __shared__ __align__(16) u16 Vsh[2][128 * 64];
  __shared__ __align__(16) u16 Vsl[2][128 * 64];
  int tid = threadIdx.x, wave = tid >> 6, lane = tid & 63;
  int l15 = lane & 15, quad = lane >> 4;
  int qp = blockIdx.x, h = blockIdx.y, b = blockIdx.z;  // qp in 0..7
  int kvh = h >> 2;

  int krow = wave * 4 + (lane >> 4);
  size_t koff = (size_t)(b * S_ + krow) * 1024 + kvh * 128
              + ((l15 * 8) ^ ((krow & 7) << 3));
  int vrow = lane >> 3;  // 0..7
  size_t voff = ((size_t)(b * 1024 + kvh * 128 + wave * 8 + vrow)) * 2048
              + (size_t)(((lane & 7) ^ vrow) << 3);
  const u16* Kgh = Kh + koff;
  const u16* Kgl = Kl + koff;
  const u16* Vgh = Vh + voff;
  const u16* Vgl = Vl + voff;

  int swz = (l15 & 7) << 3;        // read-side XOR (u16 units), all tiles

#define STAGE(T, BUF) do {                                                   \
    size_t _k0 = (size_t)(T) * 64;                                           \
    GLDS16(Kgh + _k0 * 1024,              &Ksh[BUF][(wave * 4) * 128]);      \
    GLDS16(Kgh + (_k0 + 32) * 1024,       &Ksh[BUF][(wave * 4 + 32) * 128]); \
    GLDS16(Kgl + _k0 * 1024,              &Ksl[BUF][(wave * 4) * 128]);      \
    GLDS16(Kgl + (_k0 + 32) * 1024,       &Ksl[BUF][(wave * 4 + 32) * 128]); \
    GLDS16(Vgh + _k0,                     &Vsh[BUF][(wave * 8) * 64]);       \
    GLDS16(Vgh + (size_t)64 * 2048 + _k0, &Vsh[BUF][(wave * 8 + 64) * 64]);  \
    GLDS16(Vgl + _k0,                     &Vsl[BUF][(wave * 8) * 64]);       \
    GLDS16(Vgl + (size_t)64 * 2048 + _k0, &Vsl[BUF][(wave * 8 + 64) * 64]);  \
  } while (0)

#pragma unroll 1
  for (int seg = 0; seg < 2; ++seg) {
    int qb = seg ? (15 - qp) : qp;
    int q0 = qb * 128 + wave * 16;

    bf16x8 qfh[4], qfl[4];
    const u16* qrow = Qh + (size_t)(b * S_ + q0 + l15) * 4096 + h * 128 + quad * 8;
    const u16* qrol = Ql + (size_t)(b * S_ + q0 + l15) * 4096 + h * 128 + quad * 8;
#pragma unroll
    for (int c = 0; c < 4; c++) {
      qfh[c] = *(const bf16x8*)(qrow + c * 32);
      qfl[c] = *(const bf16x8*)(qrol + c * 32);
    }
    float m_i[4], l_i[4];
#pragma unroll
    for (int r = 0; r < 4; r++) { m_i[r] = NEG_BIG; l_i[r] = 0.f; }
    f32x4 oacc[8] = {};

    int nt = 2 * qb + 2;   // number of 64-key tiles this segment
    STAGE(0, 0);
    __syncthreads();
    int cur = 0;
#pragma unroll 1
    for (int t = 0; t < nt; ++t) {
      if (t + 1 < nt) STAGE(t + 1, cur ^ 1);  // prefetch next tile first
      const u16* Kch = Ksh[cur];
      const u16* Kcl = Ksl[cur];
      const u16* Vch = Vsh[cur];
      const u16* Vcl = Vsl[cur];
      u16* PhW = Ksh[cur] + wave * 1024;  // P aliases K[cur] after mid barrier
      u16* PlW = Ksl[cur] + wave * 1024;
      int k0 = t * 64;
      bool active = (k0 <= q0 + 15);      // wave-uniform causal skip
      float p[4][4];
      if (active) {
        // ---- QK^T ----
        f32x4 sacc[4] = {};
        __builtin_amdgcn_s_setprio(1);
#pragma unroll
        for (int c = 0; c < 4; c++) {
#pragma unroll
          for (int ntl = 0; ntl < 4; ntl++) {
            int off = (ntl * 16 + l15) * 128 + ((c * 32 + quad * 8) ^ swz);
            bf16x8 kh = *(const bf16x8*)(Kch + off);
            bf16x8 kl = *(const bf16x8*)(Kcl + off);
            sacc[ntl] = __builtin_amdgcn_mfma_f32_16x16x32_bf16(qfh[c], kh, sacc[ntl], 0, 0, 0);
            sacc[ntl] = __builtin_amdgcn_mfma_f32_16x16x32_bf16(qfh[c], kl, sacc[ntl], 0, 0, 0);
            sacc[ntl] = __builtin_amdgcn_mfma_f32_16x16x32_bf16(qfl[c], kh, sacc[ntl], 0, 0, 0);
          }
        }
        __builtin_amdgcn_s_setprio(0);
        // ---- online softmax with defer-max (T13, THR=8) ----
        float cmax = NEG_BIG;
#pragma unroll
        for (int r = 0; r < 4; r++) {
          int qg = q0 + quad * 4 + r;
#pragma unroll
          for (int ntl = 0; ntl < 4; ntl++) {
            int kg = k0 + ntl * 16 + l15;
            float sv = (kg <= qg) ? sacc[ntl][r] : NEG_BIG;
            sacc[ntl][r] = sv;
            cmax = fmaxf(cmax, sv - m_i[r]);
          }
        }
        if (__all(cmax <= 8.0f)) {
          // deferred: keep m_i, no rescale (P bounded by e^8)
#pragma unroll
          for (int r = 0; r < 4; r++) {
            float ps = 0.f;
#pragma unroll
            for (int ntl = 0; ntl < 4; ntl++) {
              float pv = __expf(sacc[ntl][r] - m_i[r]);
              p[ntl][r] = pv;
              ps += pv;
            }
#pragma unroll
            for (int o = 8; o > 0; o >>= 1) ps += __shfl_xor(ps, o);
            l_i[r] += ps;
          }
        } else {
          float alpha[4];
#pragma unroll
          for (int r = 0; r < 4; r++) {
            float mr = m_i[r];
#pragma unroll
            for (int ntl = 0; ntl < 4; ntl++) mr = fmaxf(mr, sacc[ntl][r]);
#pragma unroll
            for (int o = 8; o > 0; o >>= 1) mr = fmaxf(mr, __shfl_xor(mr, o));
            float a = __expf(m_i[r] - mr);
            alpha[r] = a;
            float ps = 0.f;
#pragma unroll
            for (int ntl = 0; ntl < 4; ntl++) {
              float pv = __expf(sacc[ntl][r] - mr);
              p[ntl][r] = pv;
              ps += pv;
            }
#pragma unroll
            for (int o = 8; o > 0; o >>= 1) ps += __shfl_xor(ps, o);
            l_i[r] = l_i[r] * a + ps;
            m_i[r] = mr;
          }
#pragma unroll
          for (int dt = 0; dt < 8; dt++)
#pragma unroll
            for (int r = 0; r < 4; r++) oacc[dt][r] *= alpha[r];
        }
      }
      // mid barrier: all QK reads of K[cur] done -> safe to alias with P.
      // vmcnt(0) drain here waits on STAGE(t+1) issued a full phase ago.
      __syncthreads();
      if (active) {
        // ---- P write (per-wave region, XOR-swizzled stride-64) ----
#pragma unroll
        for (int ntl = 0; ntl < 4; ntl++)
#pragma unroll
          for (int r = 0; r < 4; r++) {
            float pv = p[ntl][r];
            u16 ph = f2bf(pv);
            int row = quad * 4 + r;
            int o = row * 64 + ((ntl * 16 + l15) ^ ((row & 7) << 3));
            PhW[o] = ph;
            PlW[o] = f2bf(pv - bf2f(ph));
          }
        // ---- PV ----
#pragma unroll
        for (int kt = 0; kt < 2; kt++) {
          bf16x8 pfh = *(const bf16x8*)(PhW + l15 * 64 + ((kt * 32 + quad * 8) ^ swz));
          bf16x8 pfl = *(const bf16x8*)(PlW + l15 * 64 + ((kt * 32 + quad * 8) ^ swz));
          __builtin_amdgcn_s_setprio(1);
#pragma unroll
          for (int dt = 0; dt < 8; dt++) {
            int off = (dt * 16 + l15) * 64 + ((kt * 32 + quad * 8) ^ swz);
            bf16x8 vh = *(const bf16x8*)(Vch + off);
            bf16x8 vl = *(const bf16x8*)(Vcl + off);
            oacc[dt] = __builtin_amdgcn_mfma_f32_16x16x32_bf16(pfh, vh, oacc[dt], 0, 0, 0);
            oacc[dt] = __builtin_amdgcn_mfma_f32_16x16x32_bf16(pfh, vl, oacc[dt], 0, 0, 0);
            oacc[dt] = __builtin_amdgcn_mfma_f32_16x16x32_bf16(pfl, vh, oacc[dt], 0, 0, 0);
          }
          __builtin_amdgcn_s_setprio(0);
        }
      }
      // end barrier: PV reads of V[cur] and P(=K[cur] alias) complete before
      // the next iteration's STAGE(t+2) overwrites this buffer.
      __syncthreads();
      cur ^= 1;
    }
    // ---- segment epilogue: write O for this q-tile ----
#pragma unroll
    for (int dt = 0; dt < 8; dt++)
#pragma unroll
      for (int r = 0; r < 4; r++) {
        int qg = q0 + quad * 4 + r;
        float ov = oacc[dt][r] / fmaxf(l_i[r], 1e-30f);
        O[(size_t)(b * S_ + qg) * 4096 + h * 128 + dt * 16 + l15] = ov;
      }
  }
#undef STAGE
}

// ---------------------------------------------------------------------------
extern "C" void kernel_launch(void* const* d_in, const int* in_sizes, int n_in,
                              void* d_out, int out_size, void* d_ws, size_t ws_size,
                              hipStream_t stream)
{
  const void* hidden = d_in[0];
  const void* cosT   = d_in[1];
  const void* sinT   = d_in[2];
  const void* Wq     = d_in[3];
  const void* Wk     = d_in[4];
  const void* Wv     = d_in[5];
  const void* Wo     = d_in[6];
  const int* idx_q  = (const int*)d_in[7];
  const int* idx_k  = (const int*)d_in[8];
  const int* idx_v  = (const int*)d_in[9];
  const int* idx_o  = (const int*)d_in[10];

  char* ws = (char*)d_ws;
  const size_t MB = 1048576;
  int*   flag = (int*)ws;
  float* Sa   = (float*)(ws + MB);            // 48 KiB
  float* Sb   = (float*)(ws + MB + 512 * 1024);
  i8* Xi   = (i8*)(ws + 2 * MB);     // 16 MiB (A-int8)
  i8* Wi   = (i8*)(ws + 34 * MB);    // 16 MiB (B-int8)
  u16* Khi = (u16*)(ws + 66 * MB);   // 8
  u16* Klo = (u16*)(ws + 74 * MB);   // 8
  u16* Vhi = (u16*)(ws + 82 * MB);   // 8
  u16* Vlo = (u16*)(ws + 90 * MB);   // 8
  u16* Qhi = (u16*)(ws + 98 * MB);   // 32
  u16* Qlo = (u16*)(ws + 130 * MB);  // 32  (total 162 MiB)
  float* AO = (float*)(ws + 2 * MB); // 64, overlays Xi+Wi (dead by then)
  i8* Oq  = (i8*)Qhi;   // overlays Q (dead after attention)
  i8* Woq = (i8*)Qlo;

  detect_k<<<1, 64, 0, stream>>>((const u16*)cosT, flag);

  // K projection (+RoPE, split)
  quant_permute_k<<<4096, 256, 0, stream>>>(hidden, idx_k, Xi, Sa, flag, 0);
  quant_permute_k<<<1024, 256, 0, stream>>>(Wk, idx_k, Wi, Sb, flag, 0);
  gemm_rope_k<<<dim3(32, 8), 256, 0, stream>>>(Xi, Wi, Sa, Sb, cosT, sinT, flag, Khi, Klo, 1024, 1.0f);
  // V projection (+transpose, split)
  quant_permute_k<<<4096, 256, 0, stream>>>(hidden, idx_v, Xi, Sa, flag, 0);
  quant_permute_k<<<1024, 256, 0, stream>>>(Wv, idx_v, Wi, Sb, flag, 0);
  gemm_vt_k<<<dim3(32, 8), 256, 0, stream>>>(Xi, Wi, Sa, Sb, Vhi, Vlo);
  // Q projection (+RoPE+scale, split)
  quant_permute_k<<<4096, 256, 0, stream>>>(hidden, idx_q, Xi, Sa, flag, 0);
  quant_permute_k<<<4096, 256, 0, stream>>>(Wq, idx_q, Wi, Sb, flag, 0);
  gemm_rope_k<<<dim3(32, 32), 256, 0, stream>>>(Xi, Wi, Sa, Sb, cosT, sinT, flag, Qhi, Qlo, 4096, 0.08838834764831843f);
  // attention (paired causal tiles: qp pairs (qp, 15-qp) -> uniform blocks)
  attn_k<<<dim3(8, 32, 2), 512, 0, stream>>>(Qhi, Qlo, Khi, Klo, Vhi, Vlo, AO);
  // output projection
  quant_permute_k<<<4096, 256, 0, stream>>>(AO, idx_o, Oq, Sa, flag, 1);
  quant_permute_k<<<4096, 256, 0, stream>>>(Wo, idx_o, Woq, Sb, flag, 0);
  gemm_out_k<<<dim3(32, 32), 256, 0, stream>>>(Oq, Woq, Sa, Sb, flag, d_out);
}

// Round 11
// 1035.563 us; speedup vs baseline: 1.6380x; 1.2220x over previous
//
#include <hip/hip_runtime.h>
#include <math.h>

// QMixtralAttention — fp32 in/out (runtime-detected, bf16 fallback).
// Numerics: integer-exact quantized GEMMs (int8 MFMA, i32 accum, per-partition
// scale fold), split-bf16 (hi+lo) flash attention, fp32 attention output.
// R1: XOR-swizzled K/V LDS tiles in attn_k. R2: KVBLK=32 — REGRESSED.
// R3: 8-wave block — NEUTRAL. R4: V-from-global — REGRESSED 2x.
// R5: attn K/V double-buffer — WIN. R6: causal-pairing — WIN (1915->1695).
// R7: gemm LDS swizzle — conflicts 5e7->0, -7.5%. R8: gemm dbuf — REGRESSED
//     (reverted). R9: GEMM datapath -> INT8 (mfma_i32_16x16x64_i8) — WIN
//     (1609->1265).
// R10: quant pipeline (the remaining ~32%): (a) fused quant3_k stages the
//      hidden row in LDS ONCE and runs all 3 projections' gather+quant from
//      LDS (hidden read 1x instead of 3x); (b) quant_permute_k (weights/AO)
//      gains the same LDS row staging — gathers hit LDS instead of
//      line-granular L1/L2. attn + GEMMs byte-identical to R9.

typedef unsigned short u16;
typedef signed char i8;
typedef __bf16 bf16x8 __attribute__((ext_vector_type(8)));
typedef float f32x4 __attribute__((ext_vector_type(4)));
typedef int i32x4 __attribute__((ext_vector_type(4)));

#define S_ 2048
#define NEG_BIG (-1e30f)

__device__ __forceinline__ float bf2f(u16 u) {
  union { unsigned int i; float f; } w; w.i = ((unsigned int)u) << 16; return w.f;
}
__device__ __forceinline__ u16 f2bf(float f) {
  union { float f; unsigned int i; } w; w.f = f;
  unsigned int i = w.i;
  i += ((i >> 16) & 1u) + 0x7fffu;  // RNE
  return (u16)(i >> 16);
}
// flag: 0 = bf16 input, 1 = fp32 input
__device__ __forceinline__ float loadf(const void* X, size_t j, int flag) {
  return flag ? ((const float*)X)[j] : bf2f(((const u16*)X)[j]);
}

#define GLDS16(g, l) __builtin_amdgcn_global_load_lds( \
    (__attribute__((address_space(1))) void*)(g),      \
    (__attribute__((address_space(3))) void*)(l), 16, 0, 0)

__global__ void detect_k(const u16* __restrict__ cosRaw, int* __restrict__ flag) {
  if (threadIdx.x == 0) *flag = (cosRaw[0] == 0x3F80u) ? 0 : 1;
}

// ---------------------------------------------------------------------------
// Quantize + permute. Partitions of the PERMUTED row: [0,3328) q7,
// [3328,3840) q31, [3840,4096) q127. R10: row staged in LDS (coalesced,
// vectorized), gathers served from LDS.
// ---------------------------------------------------------------------------
__device__ __forceinline__ float block_max(float x, float* sred, int t) {
#pragma unroll
  for (int o = 32; o > 0; o >>= 1) x = fmaxf(x, __shfl_xor(x, o));
  __syncthreads();
  if ((t & 63) == 0) sred[t >> 6] = x;
  __syncthreads();
  return fmaxf(fmaxf(sred[0], sred[1]), fmaxf(sred[2], sred[3]));
}

// Stage one 4096-element row into LDS as f32 (vectorized per dtype flag).
__device__ __forceinline__ void stage_row(
    const void* __restrict__ X, size_t row, int flag, int t, float* Lrow)
{
  if (flag) {
    const float4* X4 = (const float4*)X;
    size_t b4 = row * 1024;
#pragma unroll
    for (int i = 0; i < 4; i++) {
      float4 v = X4[b4 + i * 256 + t];
      *(float4*)&Lrow[(i * 256 + t) * 4] = v;
    }
  } else {
    const ushort4* X4 = (const ushort4*)X;
    size_t b4 = row * 1024;
#pragma unroll
    for (int i = 0; i < 4; i++) {
      ushort4 v = X4[b4 + i * 256 + t];
      float4 f;
      f.x = bf2f(v.x); f.y = bf2f(v.y); f.z = bf2f(v.z); f.w = bf2f(v.w);
      *(float4*)&Lrow[(i * 256 + t) * 4] = f;
    }
  }
}

// Gather one projection's permutation from the LDS row, quantize, write.
__device__ __forceinline__ void quant_one(
    const float* __restrict__ Lrow, const int* __restrict__ idx,
    i8* __restrict__ yr, float* __restrict__ Sout, float* sred, int t)
{
  float v[16];
#pragma unroll
  for (int i = 0; i < 16; i++) v[i] = Lrow[idx[i * 256 + t]];
  float m0 = 0.f;
#pragma unroll
  for (int i = 0; i < 13; i++) m0 = fmaxf(m0, fabsf(v[i]));
  float m1 = fmaxf(fabsf(v[13]), fabsf(v[14]));
  float m2 = fabsf(v[15]);
  float M0 = block_max(m0, sred, t);
  float M1 = block_max(m1, sred, t);
  float M2 = block_max(m2, sred, t);
  float s0 = M0 / 7.f + 1e-8f;
  float s1 = M1 / 31.f + 1e-8f;
  float s2 = M2 / 127.f + 1e-8f;
#pragma unroll
  for (int i = 0; i < 16; i++) {
    float s, qm;
    if (i < 13)      { s = s0; qm = 7.f; }
    else if (i < 15) { s = s1; qm = 31.f; }
    else             { s = s2; qm = 127.f; }
    float q = rintf(v[i] / s);
    q = fminf(fmaxf(q, -qm), qm);
    yr[i * 256 + t] = (i8)(int)q;
  }
  if (t == 0) { Sout[0] = s0; Sout[1] = s1; Sout[2] = s2; }
}

// Single-input quantize (weights, attention output).
__global__ __launch_bounds__(256) void quant_permute_k(
    const void* __restrict__ X, const int* __restrict__ idx, i8* __restrict__ Y,
    float* __restrict__ Sout, const int* __restrict__ flagp, int mode /*1=force fp32*/)
{
  __shared__ float Lrow[4096];
  __shared__ float sred[4];
  int flag = mode ? 1 : *flagp;
  int row = blockIdx.x;
  int t = threadIdx.x;
  stage_row(X, (size_t)row, flag, t, Lrow);
  __syncthreads();
  quant_one(Lrow, idx, Y + (size_t)row * 4096, Sout + (size_t)row * 3, sred, t);
}

// Fused 3-projection quantize of hidden: stage row once, gather 3 ways.
__global__ __launch_bounds__(256) void quant3_k(
    const void* __restrict__ X,
    const int* __restrict__ idxq, const int* __restrict__ idxk, const int* __restrict__ idxv,
    i8* __restrict__ Yq, i8* __restrict__ Yk, i8* __restrict__ Yv,
    float* __restrict__ Sq, float* __restrict__ Sk, float* __restrict__ Sv,
    const int* __restrict__ flagp)
{
  __shared__ float Lrow[4096];
  __shared__ float sred[4];
  int flag = *flagp;
  int row = blockIdx.x;
  int t = threadIdx.x;
  stage_row(X, (size_t)row, flag, t, Lrow);
  __syncthreads();
  size_t ro = (size_t)row * 4096;
  quant_one(Lrow, idxq, Yq + ro, Sq + (size_t)row * 3, sred, t);
  quant_one(Lrow, idxk, Yk + ro, Sk + (size_t)row * 3, sred, t);
  quant_one(Lrow, idxv, Yv + ro, Sv + (size_t)row * 3, sred, t);
}

// ---------------------------------------------------------------------------
// Integer GEMM core (INT8): C[M][N] += sum_p Sa[m,p]*Sb[n,p]*(A_p · B_p^T)
// 128x128 tile, BK=128 (i8), phases of 26/4/2 BK-iters. mfma_i32_16x16x64_i8,
// i32 accumulation (exact). LDS XOR-swizzled in 16B slots (rule #21).
// Single-buffer, 2 barriers/iter (R8 dbuf regressed — implicit wave overlap
// at 2 blocks/CU already covers staging latency).
// ---------------------------------------------------------------------------
__device__ __forceinline__ int colbase_of(int wave, int ni, int ropemap) {
  return ropemap ? (((wave >> 1) << 5) + ((ni & 1) << 4) + ((ni >> 1) << 6))
                 : (((wave >> 1) << 6) + (ni << 4));
}

__device__ __forceinline__ void gemm_core(
    const i8* __restrict__ A, const i8* __restrict__ Bm,
    const float* __restrict__ Sa, const float* __restrict__ Sb,
    int bm, int bn, int tid, int ropemap,
    i8* As, i8* Bs, f32x4 C[4][4])
{
  int wave = tid >> 6, lane = tid & 63;
  int l15 = lane & 15, quad = lane >> 4;
  int wm = (wave & 1) << 6;
  int gsw = ((lane & 7) ^ (lane >> 3)) << 4;   // bytes
  const i8* Ag = A + (size_t)(bm * 128 + wave * 32 + (lane >> 3)) * 4096 + gsw;
  const i8* Bg = Bm + (size_t)(bn * 128 + wave * 32 + (lane >> 3)) * 4096 + gsw;
  i8* AsW = As + wave * 32 * 128;
  i8* BsW = Bs + wave * 32 * 128;
  int swz = (l15 & 7) << 4;   // read-side XOR (bytes)
  i32x4 acc[4][4] = {};
  int cb[4];
#pragma unroll
  for (int ni = 0; ni < 4; ni++) cb[ni] = colbase_of(wave, ni, ropemap);
  int k0 = 0;
#pragma unroll 1
  for (int p = 0; p < 3; p++) {
    int iters = (p == 0) ? 26 : (p == 1 ? 4 : 2);
#pragma unroll 1
    for (int it = 0; it < iters; it++, k0 += 128) {
#pragma unroll
      for (int i = 0; i < 4; i++) {
        GLDS16(Ag + k0 + (size_t)(i * 8) * 4096, AsW + i * 8 * 128);
        GLDS16(Bg + k0 + (size_t)(i * 8) * 4096, BsW + i * 8 * 128);
      }
      __syncthreads();
#pragma unroll
      for (int kk = 0; kk < 2; kk++) {
        i32x4 af[4], bfv[4];
#pragma unroll
        for (int mi = 0; mi < 4; mi++)
          af[mi] = *(const i32x4*)(As + (wm + mi * 16 + l15) * 128 + ((kk * 64 + quad * 16) ^ swz));
#pragma unroll
        for (int ni = 0; ni < 4; ni++)
          bfv[ni] = *(const i32x4*)(Bs + (cb[ni] + l15) * 128 + ((kk * 64 + quad * 16) ^ swz));
#pragma unroll
        for (int mi = 0; mi < 4; mi++)
#pragma unroll
          for (int ni = 0; ni < 4; ni++)
            acc[mi][ni] = __builtin_amdgcn_mfma_i32_16x16x64_i8(af[mi], bfv[ni], acc[mi][ni], 0, 0, 0);
      }
      __syncthreads();
    }
    // partition boundary: fold scales into C (i32 -> f32, exact sums)
    float sb[4];
#pragma unroll
    for (int ni = 0; ni < 4; ni++) sb[ni] = Sb[(size_t)(bn * 128 + cb[ni] + l15) * 3 + p];
#pragma unroll
    for (int mi = 0; mi < 4; mi++)
#pragma unroll
      for (int r = 0; r < 4; r++) {
        float sa = Sa[(size_t)(bm * 128 + wm + mi * 16 + quad * 4 + r) * 3 + p];
#pragma unroll
        for (int ni = 0; ni < 4; ni++) {
          C[mi][ni][r] += sa * sb[ni] * (float)acc[mi][ni][r];
          acc[mi][ni][r] = 0;
        }
      }
  }
}

// GEMM + fused RoPE + scale + hi/lo split epilogue (Q and K projections).
__global__ __launch_bounds__(256) void gemm_rope_k(
    const i8* __restrict__ A, const i8* __restrict__ Bm,
    const float* __restrict__ Sa, const float* __restrict__ Sb,
    const void* __restrict__ Co, const void* __restrict__ Si,
    const int* __restrict__ flagp, u16* __restrict__ Qh, u16* __restrict__ Ql,
    int N, float scale)
{
  __shared__ __align__(16) i8 As[128 * 128];
  __shared__ __align__(16) i8 Bs[128 * 128];
  f32x4 C[4][4] = {};
  int tid = threadIdx.x;
  gemm_core(A, Bm, Sa, Sb, blockIdx.x, blockIdx.y, tid, 1, As, Bs, C);
  int wave = tid >> 6, lane = tid & 63, l15 = lane & 15, quad = lane >> 4;
  int wm = (wave & 1) << 6;
  int flag = *flagp;
#pragma unroll
  for (int mi = 0; mi < 4; mi++)
#pragma unroll
    for (int ni = 0; ni < 2; ni++) {
      int d1 = colbase_of(wave, ni, 1) + l15;  // < 64
#pragma unroll
      for (int r = 0; r < 4; r++) {
        int row = blockIdx.x * 128 + wm + mi * 16 + quad * 4 + r;
        float x1 = C[mi][ni][r], x2 = C[mi][ni + 2][r];
        size_t ci = (size_t)row * 128 + d1;
        float c1 = loadf(Co, ci, flag),      s1 = loadf(Si, ci, flag);
        float c2 = loadf(Co, ci + 64, flag), s2 = loadf(Si, ci + 64, flag);
        float y1 = (x1 * c1 - x2 * s1) * scale;
        float y2 = (x2 * c2 + x1 * s2) * scale;
        size_t o1 = (size_t)row * N + blockIdx.y * 128 + d1;
        u16 h1 = f2bf(y1); Qh[o1] = h1; Ql[o1] = f2bf(y1 - bf2f(h1));
        u16 h2 = f2bf(y2); Qh[o1 + 64] = h2; Ql[o1 + 64] = f2bf(y2 - bf2f(h2));
      }
    }
}

// GEMM + fused transpose + hi/lo split epilogue (V projection).
__global__ __launch_bounds__(256) void gemm_vt_k(
    const i8* __restrict__ A, const i8* __restrict__ Bm,
    const float* __restrict__ Sa, const float* __restrict__ Sb,
    u16* __restrict__ Vh, u16* __restrict__ Vl)
{
  __shared__ __align__(16) i8 As[128 * 128];
  __shared__ __align__(16) i8 Bs[128 * 128];
  f32x4 C[4][4] = {};
  int tid = threadIdx.x;
  gemm_core(A, Bm, Sa, Sb, blockIdx.x, blockIdx.y, tid, 0, As, Bs, C);
  int wave = tid >> 6, lane = tid & 63, l15 = lane & 15, quad = lane >> 4;
  int wm = (wave & 1) << 6;
#pragma unroll
  for (int mi = 0; mi < 4; mi++)
#pragma unroll
    for (int ni = 0; ni < 4; ni++) {
      int c = blockIdx.y * 128 + colbase_of(wave, ni, 0) + l15;
#pragma unroll
      for (int r = 0; r < 4; r++) {
        int row = blockIdx.x * 128 + wm + mi * 16 + quad * 4 + r;
        int b = row >> 11, s = row & 2047;
        float v = C[mi][ni][r];
        size_t o = ((size_t)(b * 1024 + c)) * 2048 + s;
        u16 h = f2bf(v); Vh[o] = h; Vl[o] = f2bf(v - bf2f(h));
      }
    }
}

// GEMM + output write (fp32 or bf16 per detected flag).
__global__ __launch_bounds__(256) void gemm_out_k(
    const i8* __restrict__ A, const i8* __restrict__ Bm,
    const float* __restrict__ Sa, const float* __restrict__ Sb,
    const int* __restrict__ flagp, void* __restrict__ Cout)
{
  __shared__ __align__(16) i8 As[128 * 128];
  __shared__ __align__(16) i8 Bs[128 * 128];
  f32x4 C[4][4] = {};
  int tid = threadIdx.x;
  gemm_core(A, Bm, Sa, Sb, blockIdx.x, blockIdx.y, tid, 0, As, Bs, C);
  int wave = tid >> 6, lane = tid & 63, l15 = lane & 15, quad = lane >> 4;
  int wm = (wave & 1) << 6;
  int flag = *flagp;
#pragma unroll
  for (int mi = 0; mi < 4; mi++)
#pragma unroll
    for (int ni = 0; ni < 4; ni++) {
      int col = blockIdx.y * 128 + colbase_of(wave, ni, 0) + l15;
#pragma unroll
      for (int r = 0; r < 4; r++) {
        int row = blockIdx.x * 128 + wm + mi * 16 + quad * 4 + r;
        if (flag) ((float*)Cout)[(size_t)row * 4096 + col] = C[mi][ni][r];
        else      ((u16*)Cout)[(size_t)row * 4096 + col] = f2bf(C[mi][ni][r]);
      }
    }
}

// ---------------------------------------------------------------------------
// Causal flash attention, split-bf16 (3-term MFMA) QK^T and PV. O is fp32.
// R6 structure (unchanged): 8 waves, 128 q-rows/segment, KVBLK=64, double-
// buffered K/V (128 KiB LDS), causal pairing (qb, 15-qb) -> uniform 36
// staged tiles/block, 512-block grid.
// ---------------------------------------------------------------------------
__global__ __launch_bounds__(512) void attn_k(
    const u16* __restrict__ Qh, const u16* __restrict__ Ql,
    const u16* __restrict__ Kh, const u16* __restrict__ Kl,
    const u16* __restrict__ Vh, const u16* __restrict__ Vl,
    float* __restrict__ O)
{
  __shared__ __align__(16) u16 Ksh[2][64 * 128];
  __shared__ __align__(16) u16 Ksl[2][64 * 128];
  __shared__ __align__(16) u16 Vsh[2][128 * 64];
  __shared__ __align__(16) u16 Vsl[2][128 * 64];
  int tid = threadIdx.x, wave = tid >> 6, lane = tid & 63;
  int l15 = lane & 15, quad = lane >> 4;
  int qp = blockIdx.x, h = blockIdx.y, b = blockIdx.z;  // qp in 0..7
  int kvh = h >> 2;

  int krow = wave * 4 + (lane >> 4);
  size_t koff = (size_t)(b * S_ + krow) * 1024 + kvh * 128
              + ((l15 * 8) ^ ((krow & 7) << 3));
  int vrow = lane >> 3;  // 0..7
  size_t voff = ((size_t)(b * 1024 + kvh * 128 + wave * 8 + vrow)) * 2048
              + (size_t)(((lane & 7) ^ vrow) << 3);
  const u16* Kgh = Kh + koff;
  const u16* Kgl = Kl + koff;
  const u16* Vgh = Vh + voff;
  const u16* Vgl = Vl + voff;

  int swz = (l15 & 7) << 3;        // read-side XOR (u16 units), all tiles

#define STAGE(T, BUF) do {                                                   \
    size_t _k0 = (size_t)(T) * 64;                                           \
    GLDS16(Kgh + _k0 * 1024,              &Ksh[BUF][(wave * 4) * 128]);      \
    GLDS16(Kgh + (_k0 + 32) * 1024,       &Ksh[BUF][(wave * 4 + 32) * 128]); \
    GLDS16(Kgl + _k0 * 1024,              &Ksl[BUF][(wave * 4) * 128]);      \
    GLDS16(Kgl + (_k0 + 32) * 1024,       &Ksl[BUF][(wave * 4 + 32) * 128]); \
    GLDS16(Vgh + _k0,                     &Vsh[BUF][(wave * 8) * 64]);       \
    GLDS16(Vgh + (size_t)64 * 2048 + _k0, &Vsh[BUF][(wave * 8 + 64) * 64]);  \
    GLDS16(Vgl + _k0,                     &Vsl[BUF][(wave * 8) * 64]);       \
    GLDS16(Vgl + (size_t)64 * 2048 + _k0, &Vsl[BUF][(wave * 8 + 64) * 64]);  \
  } while (0)

#pragma unroll 1
  for (int seg = 0; seg < 2; ++seg) {
    int qb = seg ? (15 - qp) : qp;
    int q0 = qb * 128 + wave * 16;

    bf16x8 qfh[4], qfl[4];
    const u16* qrow = Qh + (size_t)(b * S_ + q0 + l15) * 4096 + h * 128 + quad * 8;
    const u16* qrol = Ql + (size_t)(b * S_ + q0 + l15) * 4096 + h * 128 + quad * 8;
#pragma unroll
    for (int c = 0; c < 4; c++) {
      qfh[c] = *(const bf16x8*)(qrow + c * 32);
      qfl[c] = *(const bf16x8*)(qrol + c * 32);
    }
    float m_i[4], l_i[4];
#pragma unroll
    for (int r = 0; r < 4; r++) { m_i[r] = NEG_BIG; l_i[r] = 0.f; }
    f32x4 oacc[8] = {};

    int nt = 2 * qb + 2;   // number of 64-key tiles this segment
    STAGE(0, 0);
    __syncthreads();
    int cur = 0;
#pragma unroll 1
    for (int t = 0; t < nt; ++t) {
      if (t + 1 < nt) STAGE(t + 1, cur ^ 1);  // prefetch next tile first
      const u16* Kch = Ksh[cur];
      const u16* Kcl = Ksl[cur];
      const u16* Vch = Vsh[cur];
      const u16* Vcl = Vsl[cur];
      u16* PhW = Ksh[cur] + wave * 1024;  // P aliases K[cur] after mid barrier
      u16* PlW = Ksl[cur] + wave * 1024;
      int k0 = t * 64;
      bool active = (k0 <= q0 + 15);      // wave-uniform causal skip
      float p[4][4];
      if (active) {
        // ---- QK^T ----
        f32x4 sacc[4] = {};
        __builtin_amdgcn_s_setprio(1);
#pragma unroll
        for (int c = 0; c < 4; c++) {
#pragma unroll
          for (int ntl = 0; ntl < 4; ntl++) {
            int off = (ntl * 16 + l15) * 128 + ((c * 32 + quad * 8) ^ swz);
            bf16x8 kh = *(const bf16x8*)(Kch + off);
            bf16x8 kl = *(const bf16x8*)(Kcl + off);
            sacc[ntl] = __builtin_amdgcn_mfma_f32_16x16x32_bf16(qfh[c], kh, sacc[ntl], 0, 0, 0);
            sacc[ntl] = __builtin_amdgcn_mfma_f32_16x16x32_bf16(qfh[c], kl, sacc[ntl], 0, 0, 0);
            sacc[ntl] = __builtin_amdgcn_mfma_f32_16x16x32_bf16(qfl[c], kh, sacc[ntl], 0, 0, 0);
          }
        }
        __builtin_amdgcn_s_setprio(0);
        // ---- online softmax with defer-max (T13, THR=8) ----
        float cmax = NEG_BIG;
#pragma unroll
        for (int r = 0; r < 4; r++) {
          int qg = q0 + quad * 4 + r;
#pragma unroll
          for (int ntl = 0; ntl < 4; ntl++) {
            int kg = k0 + ntl * 16 + l15;
            float sv = (kg <= qg) ? sacc[ntl][r] : NEG_BIG;
            sacc[ntl][r] = sv;
            cmax = fmaxf(cmax, sv - m_i[r]);
          }
        }
        if (__all(cmax <= 8.0f)) {
          // deferred: keep m_i, no rescale (P bounded by e^8)
#pragma unroll
          for (int r = 0; r < 4; r++) {
            float ps = 0.f;
#pragma unroll
            for (int ntl = 0; ntl < 4; ntl++) {
              float pv = __expf(sacc[ntl][r] - m_i[r]);
              p[ntl][r] = pv;
              ps += pv;
            }
#pragma unroll
            for (int o = 8; o > 0; o >>= 1) ps += __shfl_xor(ps, o);
            l_i[r] += ps;
          }
        } else {
          float alpha[4];
#pragma unroll
          for (int r = 0; r < 4; r++) {
            float mr = m_i[r];
#pragma unroll
            for (int ntl = 0; ntl < 4; ntl++) mr = fmaxf(mr, sacc[ntl][r]);
#pragma unroll
            for (int o = 8; o > 0; o >>= 1) mr = fmaxf(mr, __shfl_xor(mr, o));
            float a = __expf(m_i[r] - mr);
            alpha[r] = a;
            float ps = 0.f;
#pragma unroll
            for (int ntl = 0; ntl < 4; ntl++) {
              float pv = __expf(sacc[ntl][r] - mr);
              p[ntl][r] = pv;
              ps += pv;
            }
#pragma unroll
            for (int o = 8; o > 0; o >>= 1) ps += __shfl_xor(ps, o);
            l_i[r] = l_i[r] * a + ps;
            m_i[r] = mr;
          }
#pragma unroll
          for (int dt = 0; dt < 8; dt++)
#pragma unroll
            for (int r = 0; r < 4; r++) oacc[dt][r] *= alpha[r];
        }
      }
      // mid barrier: all QK reads of K[cur] done -> safe to alias with P.
      // vmcnt(0) drain here waits on STAGE(t+1) issued a full phase ago.
      __syncthreads();
      if (active) {
        // ---- P write (per-wave region, XOR-swizzled stride-64) ----
#pragma unroll
        for (int ntl = 0; ntl < 4; ntl++)
#pragma unroll
          for (int r = 0; r < 4; r++) {
            float pv = p[ntl][r];
            u16 ph = f2bf(pv);
            int row = quad * 4 + r;
            int o = row * 64 + ((ntl * 16 + l15) ^ ((row & 7) << 3));
            PhW[o] = ph;
            PlW[o] = f2bf(pv - bf2f(ph));
          }
        // ---- PV ----
#pragma unroll
        for (int kt = 0; kt < 2; kt++) {
          bf16x8 pfh = *(const bf16x8*)(PhW + l15 * 64 + ((kt * 32 + quad * 8) ^ swz));
          bf16x8 pfl = *(const bf16x8*)(PlW + l15 * 64 + ((kt * 32 + quad * 8) ^ swz));
          __builtin_amdgcn_s_setprio(1);
#pragma unroll
          for (int dt = 0; dt < 8; dt++) {
            int off = (dt * 16 + l15) * 64 + ((kt * 32 + quad * 8) ^ swz);
            bf16x8 vh = *(const bf16x8*)(Vch + off);
            bf16x8 vl = *(const bf16x8*)(Vcl + off);
            oacc[dt] = __builtin_amdgcn_mfma_f32_16x16x32_bf16(pfh, vh, oacc[dt], 0, 0, 0);
            oacc[dt] = __builtin_amdgcn_mfma_f32_16x16x32_bf16(pfh, vl, oacc[dt], 0, 0, 0);
            oacc[dt] = __builtin_amdgcn_mfma_f32_16x16x32_bf16(pfl, vh, oacc[dt], 0, 0, 0);
          }
          __builtin_amdgcn_s_setprio(0);
        }
      }
      // end barrier: PV reads of V[cur] and P(=K[cur] alias) complete before
      // the next iteration's STAGE(t+2) overwrites this buffer.
      __syncthreads();
      cur ^= 1;
    }
    // ---- segment epilogue: write O for this q-tile ----
#pragma unroll
    for (int dt = 0; dt < 8; dt++)
#pragma unroll
      for (int r = 0; r < 4; r++) {
        int qg = q0 + quad * 4 + r;
        float ov = oacc[dt][r] / fmaxf(l_i[r], 1e-30f);
        O[(size_t)(b * S_ + qg) * 4096 + h * 128 + dt * 16 + l15] = ov;
      }
  }
#undef STAGE
}

// ---------------------------------------------------------------------------
extern "C" void kernel_launch(void* const* d_in, const int* in_sizes, int n_in,
                              void* d_out, int out_size, void* d_ws, size_t ws_size,
                              hipStream_t stream)
{
  const void* hidden = d_in[0];
  const void* cosT   = d_in[1];
  const void* sinT   = d_in[2];
  const void* Wq     = d_in[3];
  const void* Wk     = d_in[4];
  const void* Wv     = d_in[5];
  const void* Wo     = d_in[6];
  const int* idx_q  = (const int*)d_in[7];
  const int* idx_k  = (const int*)d_in[8];
  const int* idx_v  = (const int*)d_in[9];
  const int* idx_o  = (const int*)d_in[10];

  char* ws = (char*)d_ws;
  const size_t MB = 1048576;
  int*   flag  = (int*)ws;
  float* Sa_k  = (float*)(ws + MB);                 // 48 KiB each
  float* Sa_v  = (float*)(ws + MB + 64 * 1024);
  float* Sa_q  = (float*)(ws + MB + 128 * 1024);
  float* Sb    = (float*)(ws + MB + 512 * 1024);
  i8* Xq_k = (i8*)(ws + 2 * MB);     // 16 MiB
  i8* Xq_v = (i8*)(ws + 18 * MB);    // 16 MiB
  i8* Xq_q = (i8*)(ws + 34 * MB);    // 16 MiB
  i8* Wi   = (i8*)(ws + 50 * MB);    // 16 MiB (serial per weight GEMM)
  u16* Khi = (u16*)(ws + 66 * MB);   // 8
  u16* Klo = (u16*)(ws + 74 * MB);   // 8
  u16* Vhi = (u16*)(ws + 82 * MB);   // 8
  u16* Vlo = (u16*)(ws + 90 * MB);   // 8
  u16* Qhi = (u16*)(ws + 98 * MB);   // 32
  u16* Qlo = (u16*)(ws + 130 * MB);  // 32  (total 162 MiB)
  float* AO = (float*)(ws + 2 * MB); // 64 (2..66), overlays Xq_*/Wi (dead by attn)
  i8* Oq  = (i8*)Qhi;   // overlays Q (dead after attention)
  i8* Woq = (i8*)Qlo;

  detect_k<<<1, 64, 0, stream>>>((const u16*)cosT, flag);

  // Fused hidden quant: read hidden once, produce all 3 projections' int8.
  quant3_k<<<4096, 256, 0, stream>>>(hidden, idx_q, idx_k, idx_v,
                                     Xq_q, Xq_k, Xq_v, Sa_q, Sa_k, Sa_v, flag);
  // K projection (+RoPE, split)
  quant_permute_k<<<1024, 256, 0, stream>>>(Wk, idx_k, Wi, Sb, flag, 0);
  gemm_rope_k<<<dim3(32, 8), 256, 0, stream>>>(Xq_k, Wi, Sa_k, Sb, cosT, sinT, flag, Khi, Klo, 1024, 1.0f);
  // V projection (+transpose, split)
  quant_permute_k<<<1024, 256, 0, stream>>>(Wv, idx_v, Wi, Sb, flag, 0);
  gemm_vt_k<<<dim3(32, 8), 256, 0, stream>>>(Xq_v, Wi, Sa_v, Sb, Vhi, Vlo);
  // Q projection (+RoPE+scale, split)
  quant_permute_k<<<4096, 256, 0, stream>>>(Wq, idx_q, Wi, Sb, flag, 0);
  gemm_rope_k<<<dim3(32, 32), 256, 0, stream>>>(Xq_q, Wi, Sa_q, Sb, cosT, sinT, flag, Qhi, Qlo, 4096, 0.08838834764831843f);
  // attention (paired causal tiles: qp pairs (qp, 15-qp) -> uniform blocks)
  attn_k<<<dim3(8, 32, 2), 512, 0, stream>>>(Qhi, Qlo, Khi, Klo, Vhi, Vlo, AO);
  // output projection (AO quant reuses Sa_k; Wo int8 goes to Woq region)
  quant_permute_k<<<4096, 256, 0, stream>>>(AO, idx_o, Oq, Sa_k, flag, 1);
  quant_permute_k<<<4096, 256, 0, stream>>>(Wo, idx_o, Woq, Sb, flag, 0);
  gemm_out_k<<<dim3(32, 32), 256, 0, stream>>>(Oq, Woq, Sa_k, Sb, flag, d_out);
}